// Round 5
// baseline (513.596 us; speedup 1.0000x reference)
//
#include <hip/hip_runtime.h>
#include <hip/hip_bf16.h>

// Problem constants (from reference setup_inputs)
#define NB   8
#define NN   16384
#define NK   9
#define NCF  64          // feature channels
#define NCIN 66          // 2 + 64 concat channels
#define NCO  64
#define JTOT (NCIN * NK) // 594
#define KPAD 608         // 19 * 32 (MFMA K-steps)
#define ROWE 610         // LDS wf row length in bf16 elems (odd dword stride -> conflict-free)
#define ROWU (ROWE / 2)  // 305 uints per row
#define MT   32          // points per block (32 -> 39 KB LDS -> 3-4 blocks/CU, vs 2 at MT=64)

typedef __attribute__((ext_vector_type(8))) short frag8;  // 8 bf16 (4 VGPRs)
typedef __attribute__((ext_vector_type(4))) float frag4;  // 4 fp32 acc

__device__ __forceinline__ float leakyf(float x) { return fmaxf(x, 0.1f * x); }

// bf16 RNE — EXACTLY the R2 path (absmax 0.125, passed twice). R3/R4 post-mortem:
// fp16 + launch_bounds(256,2) + prefetch-hoist produced UNEXPLAINED error growth
// (0.344 bf16 / 0.277 fp16 — not mantissa-limited); reverted wholesale.
__device__ __forceinline__ unsigned short f2bf(float x) {
  __hip_bfloat16 h = __float2bfloat16(x);
  unsigned short us;
  __builtin_memcpy(&us, &h, 2);
  return us;
}

// Repack lin_w [64][594] fp32 (row co, col o*66+c) into bf16 lb[co][j], j = c*9+o, zero-padded to 608.
__global__ void prep_lb_kernel(const float* __restrict__ lin_w, unsigned short* __restrict__ lb) {
  int idx = blockIdx.x * 256 + threadIdx.x;
  if (idx >= NCO * KPAD) return;
  int co = idx / KPAD;
  int j  = idx - co * KPAD;
  float v = 0.f;
  if (j < JTOT) {
    int c = j / NK;
    int o = j - c * NK;
    v = lin_w[co * JTOT + o * NCIN + c];
  }
  lb[idx] = f2bf(v);
}

// NO second launch_bounds arg (R3 superstition): keep the R2-proven compile regime.
__global__ __launch_bounds__(256) void pointconv_kernel(
    const float* __restrict__ xy,   // [8][2][16384][9]
    const float* __restrict__ feat, // [8][64][16384][9]
    const float* __restrict__ w1,   // [9][2]
    const float* __restrict__ b1,   // [9]
    const float* __restrict__ w2,   // [9][9]
    const float* __restrict__ b2,   // [9]
    const unsigned short* __restrict__ lb, // bf16 [64][608]
    const float* __restrict__ lin_b,       // [64]
    float* __restrict__ out) {             // [8][64][16384]
  __shared__ unsigned int wfu[MT * ROWU];  // 39,040 B static — no dynamic-LDS attribute needed

  const int t  = threadIdx.x;
  const int p  = t & 31;          // point within tile
  const int g  = t >> 5;          // channel group (8 groups of 32 threads)
  const int b  = blockIdx.x >> 9; // 512 tiles per batch
  const int n0 = (blockIdx.x & 511) << 5;
  const int n  = n0 + p;

  // ---- Phase 1a: WeightNet -> wv[9][9] (redundant per group; registers) ----
  float wv[9][9];
  {
    float x0[9], x1[9];
    const float* x0p = xy + (((size_t)b * 2 + 0) * NN + n) * NK;
    const float* x1p = xy + (((size_t)b * 2 + 1) * NN + n) * NK;
#pragma unroll
    for (int k = 0; k < NK; ++k) { x0[k] = x0p[k]; x1[k] = x1p[k]; }
#pragma unroll
    for (int k = 0; k < NK; ++k) {
      float h[9];
#pragma unroll
      for (int o = 0; o < 9; ++o)
        h[o] = leakyf(w1[2 * o] * x0[k] + w1[2 * o + 1] * x1[k] + b1[o]);
#pragma unroll
      for (int o = 0; o < 9; ++o) {
        float s = b2[o];
#pragma unroll
        for (int o2 = 0; o2 < 9; ++o2) s += w2[o * 9 + o2] * h[o2];
        wv[o][k] = leakyf(s);
      }
    }
  }

  // ---- Phase 1b: wf[j = c*9+o] = sum_k wv[o][k] * knn[c][k], packed bf16 pairs to LDS ----
  // Channel split: group g covers [8g, 8g+8); group 7 also covers 64,65. All chunk starts even.
  const int cbeg = g * 8;
  float f0[4][9], f1[4][9];

  auto ldc = [&](float (&dst)[9], int c) {
    const float* fp = (c < 2)
        ? xy   + (((size_t)b * 2   + c)       * NN + n) * NK
        : feat + (((size_t)b * NCF + (c - 2)) * NN + n) * NK;
#pragma unroll
    for (int k = 0; k < NK; ++k) dst[k] = fp[k];
  };

  auto comp4 = [&](float (&f)[4][9], int c0) {
    unsigned int wo[18];
#pragma unroll
    for (int m = 0; m < 18; ++m) wo[m] = 0;
#pragma unroll
    for (int cc = 0; cc < 4; ++cc) {
#pragma unroll
      for (int o = 0; o < 9; ++o) {
        float s = wv[o][0] * f[cc][0];
#pragma unroll
        for (int k = 1; k < NK; ++k) s += wv[o][k] * f[cc][k];
        int v = cc * 9 + o;
        wo[v >> 1] |= (unsigned int)f2bf(s) << (16 * (v & 1));
      }
    }
    unsigned int* dst = wfu + p * ROWU + ((c0 * 9) >> 1);  // c0 even -> exact
#pragma unroll
    for (int m = 0; m < 18; ++m) dst[m] = wo[m];
  };

  auto comp2 = [&](float (&f)[4][9], int c0) {  // uses f[0],f[1]
    unsigned int wo[9];
#pragma unroll
    for (int m = 0; m < 9; ++m) wo[m] = 0;
#pragma unroll
    for (int cc = 0; cc < 2; ++cc) {
#pragma unroll
      for (int o = 0; o < 9; ++o) {
        float s = wv[o][0] * f[cc][0];
#pragma unroll
        for (int k = 1; k < NK; ++k) s += wv[o][k] * f[cc][k];
        int v = cc * 9 + o;
        wo[v >> 1] |= (unsigned int)f2bf(s) << (16 * (v & 1));
      }
    }
    unsigned int* dst = wfu + p * ROWU + ((c0 * 9) >> 1);
#pragma unroll
    for (int m = 0; m < 9; ++m) dst[m] = wo[m];
  };

  // Both chunks (the group's entire range) prefetched up front: 72 dwords in
  // flight per thread before the first compute -> deep MLP at higher occupancy.
#pragma unroll
  for (int cc = 0; cc < 4; ++cc) ldc(f0[cc], cbeg + cc);
#pragma unroll
  for (int cc = 0; cc < 4; ++cc) ldc(f1[cc], cbeg + 4 + cc);
  comp4(f0, cbeg + 0);
  if (g == 7) { ldc(f0[0], 64); ldc(f0[1], 65); }
  comp4(f1, cbeg + 4);
  if (g == 7) {
    comp2(f0, 64);
    // zero-pad j in [594, 608): uint indices 297..303
    unsigned int* dst = wfu + p * ROWU + 297;
#pragma unroll
    for (int m = 0; m < 7; ++m) dst[m] = 0;
  }
  __syncthreads();

  // ---- Phase 2: [32 pts x 608] @ [608 x 64 co] via mfma_f32_16x16x32_bf16 ----
  const int lane = t & 63;
  const int wvw  = t >> 6;      // wave id 0..3
  const int r    = wvw & 1;     // row-tile: points [16r, 16r+16)
  const int hh   = wvw >> 1;    // col half: co tiles {2hh, 2hh+1}
  const int col  = lane & 15;
  const int q    = lane >> 4;

  frag4 acc[2];
#pragma unroll
  for (int ct = 0; ct < 2; ++ct) acc[ct] = frag4{0.f, 0.f, 0.f, 0.f};

  const int arow_u = (16 * r + col) * ROWU;

  for (int s = 0; s < KPAD / 32; ++s) {
    const int k0 = 32 * s;
    union { unsigned int u[4]; frag8 v; } ua;
    const int abase = arow_u + ((k0 + q * 8) >> 1);
    ua.u[0] = wfu[abase + 0];
    ua.u[1] = wfu[abase + 1];
    ua.u[2] = wfu[abase + 2];
    ua.u[3] = wfu[abase + 3];
#pragma unroll
    for (int ct = 0; ct < 2; ++ct) {
      const frag8* bp = (const frag8*)(lb + ((2 * hh + ct) * 16 + col) * KPAD + k0 + q * 8);
      acc[ct] = __builtin_amdgcn_mfma_f32_16x16x32_bf16(ua.v, *bp, acc[ct], 0, 0, 0);
    }
  }

  // ---- Epilogue: bias + leaky, float4 stores (D: col -> co, row = q*4+reg -> point) ----
  float* outbase = out + ((size_t)b * NCO) * NN;
  const int nrow = n0 + 16 * r + q * 4;
#pragma unroll
  for (int ct = 0; ct < 2; ++ct) {
    const int co = (2 * hh + ct) * 16 + col;
    const float bias = lin_b[co];
    float4 v;
    v.x = leakyf(acc[ct][0] + bias);
    v.y = leakyf(acc[ct][1] + bias);
    v.z = leakyf(acc[ct][2] + bias);
    v.w = leakyf(acc[ct][3] + bias);
    *(float4*)(outbase + (size_t)co * NN + nrow) = v;
  }
}

extern "C" void kernel_launch(void* const* d_in, const int* in_sizes, int n_in,
                              void* d_out, int out_size, void* d_ws, size_t ws_size,
                              hipStream_t stream) {
  const float* xy    = (const float*)d_in[0];
  const float* feat  = (const float*)d_in[1];
  const float* w1    = (const float*)d_in[2];
  const float* b1    = (const float*)d_in[3];
  const float* w2    = (const float*)d_in[4];
  const float* b2    = (const float*)d_in[5];
  const float* lw    = (const float*)d_in[6];
  const float* lbias = (const float*)d_in[7];
  float* out = (float*)d_out;
  unsigned short* lb = (unsigned short*)d_ws; // 64*608*2 = 77824 B

  prep_lb_kernel<<<(NCO * KPAD + 255) / 256, 256, 0, stream>>>(lw, lb);
  pointconv_kernel<<<NB * (NN / MT), 256, 0, stream>>>(
      xy, feat, w1, b1, w2, b2, lb, lbias, out);
}

// Round 6
// 474.785 us; speedup vs baseline: 1.0817x; 1.0817x over previous
//
#include <hip/hip_runtime.h>
#include <hip/hip_bf16.h>

// Problem constants (from reference setup_inputs)
#define NB   8
#define NN   16384
#define NK   9
#define NCF  64          // feature channels
#define NCIN 66          // 2 + 64 concat channels
#define NCO  64
#define JTOT (NCIN * NK) // 594
#define KPAD 608         // 19 * 32 (MFMA K-steps)
#define ROWE 610         // LDS wf row length in bf16 elems (odd dword stride -> conflict-free)
#define ROWU (ROWE / 2)  // 305 uints per row
#define MT   32          // points per block
#define CHC  8           // feature channels per staging chunk
#define NCHUNK (NCF / CHC)        // 8 chunks
#define ROWB (MT * NK * 4)        // 1152 B per staged channel row
#define TRC  (CHC * ROWB / 16)    // 576 16B transfers per chunk
#define INSC (TRC / 64)           // 9 wave-instructions per chunk

typedef __attribute__((ext_vector_type(8))) short frag8;  // 8 bf16 (4 VGPRs)
typedef __attribute__((ext_vector_type(4))) float frag4;  // 4 fp32 acc

__device__ __forceinline__ float leakyf(float x) { return fmaxf(x, 0.1f * x); }

// bf16 RNE — the R2/R5-proven numerics path (absmax 0.125). Dot-product
// structure below is kept bit-identical; only WHO loads the data changed.
__device__ __forceinline__ unsigned short f2bf(float x) {
  __hip_bfloat16 h = __float2bfloat16(x);
  unsigned short us;
  __builtin_memcpy(&us, &h, 2);
  return us;
}

// Repack lin_w [64][594] fp32 (row co, col o*66+c) into bf16 lb[co][j], j = c*9+o, zero-padded to 608.
__global__ void prep_lb_kernel(const float* __restrict__ lin_w, unsigned short* __restrict__ lb) {
  int idx = blockIdx.x * 256 + threadIdx.x;
  if (idx >= NCO * KPAD) return;
  int co = idx / KPAD;
  int j  = idx - co * KPAD;
  float v = 0.f;
  if (j < JTOT) {
    int c = j / NK;
    int o = j - c * NK;
    v = lin_w[co * JTOT + o * NCIN + c];
  }
  lb[idx] = f2bf(v);
}

__global__ __launch_bounds__(256) void pointconv_kernel(
    const float* __restrict__ xy,   // [8][2][16384][9]
    const float* __restrict__ feat, // [8][64][16384][9]
    const float* __restrict__ w1,   // [9][2]
    const float* __restrict__ b1,   // [9]
    const float* __restrict__ w2,   // [9][9]
    const float* __restrict__ b2,   // [9]
    const unsigned short* __restrict__ lb, // bf16 [64][608]
    const float* __restrict__ lin_b,       // [64]
    float* __restrict__ out) {             // [8][64][16384]
  __shared__ unsigned short wfs[MT * ROWE]; // 39,040 B
  __shared__ float stage[CHC * MT * NK];    // 9,216 B staging buffer (DMA target)

  const int t    = threadIdx.x;
  const int p    = t & 31;          // point within tile
  const int g    = t >> 5;          // channel group (8 groups of 32 threads)
  const int lane = t & 63;
  const int wvid = t >> 6;          // wave id 0..3
  const int b    = blockIdx.x >> 9; // 512 tiles per batch
  const int n0   = (blockIdx.x & 511) << 5;
  const int n    = n0 + p;

  // ---- Async staging: global feat rows -> LDS via global_load_lds (no VGPR
  // round-trip; the in-flight queue lives in the DMA engine, so the register
  // allocator cannot serialize it — R2/R3/R5 post-mortem). Global side is a
  // per-lane gather; LDS side is uniform base + lane*16 (HW requirement). ----
  auto stage_chunk = [&](int ch) {
    const char* gb = (const char*)feat +
        (((size_t)b * NCF + ch * CHC) * NN + (size_t)n0) * (NK * 4);
    for (int i = wvid; i < INSC; i += 4) {   // 9 instrs: wave0 gets 3, others 2
      unsigned j   = i * 64 + lane;          // transfer index within chunk
      unsigned cl  = j / 72u;                // channel within chunk (72 x 16B per row)
      unsigned rem = j - cl * 72u;           // 16B-slot within the 1152B row
      const char* gp = gb + (size_t)cl * ((size_t)NN * NK * 4) + rem * 16;
      const char* lp = (const char*)stage + i * 1024;  // wave-uniform base
      __builtin_amdgcn_global_load_lds(
          (const __attribute__((address_space(1))) unsigned int*)gp,
          (__attribute__((address_space(3))) unsigned int*)lp,
          16, 0, 0);
    }
  };

  stage_chunk(0);  // in flight while WeightNet computes

  // ---- Phase 1a: WeightNet -> wv[9][9] (registers; math identical to R2/R5) ----
  float wv[9][9];
  float x0[9], x1[9];
  {
    const float* x0p = xy + (((size_t)b * 2 + 0) * NN + n) * NK;
    const float* x1p = xy + (((size_t)b * 2 + 1) * NN + n) * NK;
#pragma unroll
    for (int k = 0; k < NK; ++k) { x0[k] = x0p[k]; x1[k] = x1p[k]; }
#pragma unroll
    for (int k = 0; k < NK; ++k) {
      float h[9];
#pragma unroll
      for (int o = 0; o < 9; ++o)
        h[o] = leakyf(w1[2 * o] * x0[k] + w1[2 * o + 1] * x1[k] + b1[o]);
#pragma unroll
      for (int o = 0; o < 9; ++o) {
        float s = b2[o];
#pragma unroll
        for (int o2 = 0; o2 < 9; ++o2) s += w2[o * 9 + o2] * h[o2];
        wv[o][k] = leakyf(s);
      }
    }
  }

  // ---- xy channels (concat c=0,1) from registers; zero-pad tail ----
  if (g == 0) {
#pragma unroll
    for (int cc = 0; cc < 2; ++cc) {
#pragma unroll
      for (int o = 0; o < 9; ++o) {
        float s = wv[o][0] * (cc ? x1[0] : x0[0]);
#pragma unroll
        for (int k = 1; k < NK; ++k) s += wv[o][k] * (cc ? x1[k] : x0[k]);
        wfs[p * ROWE + cc * 9 + o] = f2bf(s);
      }
    }
  }
  if (g == 1) {
#pragma unroll
    for (int m = 0; m < KPAD - JTOT; ++m) wfs[p * ROWE + JTOT + m] = 0;
  }

  // ---- Phase 1b: chunked stage->barrier->compute loop. Latency hidden by
  // 3 blocks/CU interleaving (m114 implicit overlap), not by registers. ----
  for (int ch = 0; ch < NCHUNK; ++ch) {
    __syncthreads();  // barrier drains vmcnt -> staged chunk visible to all
    {
      const float* sp = stage + g * (MT * NK) + p * NK;
      float f[9];
#pragma unroll
      for (int k = 0; k < NK; ++k) f[k] = sp[k];
      const int c = 2 + ch * CHC + g;  // concat channel index
      unsigned short* wr = wfs + p * ROWE + c * 9;
#pragma unroll
      for (int o = 0; o < 9; ++o) {
        float s = wv[o][0] * f[0];
#pragma unroll
        for (int k = 1; k < NK; ++k) s += wv[o][k] * f[k];
        wr[o] = f2bf(s);
      }
    }
    if (ch + 1 < NCHUNK) {
      __syncthreads();        // everyone done reading the buffer
      stage_chunk(ch + 1);    // refill
    }
  }
  __syncthreads();

  // ---- Phase 2: [32 pts x 608] @ [608 x 64 co] via mfma_f32_16x16x32_bf16 (R5 verbatim) ----
  const unsigned int* wfu = (const unsigned int*)wfs;
  const int r    = wvid & 1;     // row-tile: points [16r, 16r+16)
  const int hh   = wvid >> 1;    // col half: co tiles {2hh, 2hh+1}
  const int col  = lane & 15;
  const int q    = lane >> 4;

  frag4 acc[2];
#pragma unroll
  for (int ct = 0; ct < 2; ++ct) acc[ct] = frag4{0.f, 0.f, 0.f, 0.f};

  const int arow_u = (16 * r + col) * ROWU;

  for (int s = 0; s < KPAD / 32; ++s) {
    const int k0 = 32 * s;
    union { unsigned int u[4]; frag8 v; } ua;
    const int abase = arow_u + ((k0 + q * 8) >> 1);
    ua.u[0] = wfu[abase + 0];
    ua.u[1] = wfu[abase + 1];
    ua.u[2] = wfu[abase + 2];
    ua.u[3] = wfu[abase + 3];
#pragma unroll
    for (int ct = 0; ct < 2; ++ct) {
      const frag8* bp = (const frag8*)(lb + ((2 * hh + ct) * 16 + col) * KPAD + k0 + q * 8);
      acc[ct] = __builtin_amdgcn_mfma_f32_16x16x32_bf16(ua.v, *bp, acc[ct], 0, 0, 0);
    }
  }

  // ---- Epilogue: bias + leaky, float4 stores (D: col -> co, row = q*4+reg -> point) ----
  float* outbase = out + ((size_t)b * NCO) * NN;
  const int nrow = n0 + 16 * r + q * 4;
#pragma unroll
  for (int ct = 0; ct < 2; ++ct) {
    const int co = (2 * hh + ct) * 16 + col;
    const float bias = lin_b[co];
    float4 v;
    v.x = leakyf(acc[ct][0] + bias);
    v.y = leakyf(acc[ct][1] + bias);
    v.z = leakyf(acc[ct][2] + bias);
    v.w = leakyf(acc[ct][3] + bias);
    *(float4*)(outbase + (size_t)co * NN + nrow) = v;
  }
}

extern "C" void kernel_launch(void* const* d_in, const int* in_sizes, int n_in,
                              void* d_out, int out_size, void* d_ws, size_t ws_size,
                              hipStream_t stream) {
  const float* xy    = (const float*)d_in[0];
  const float* feat  = (const float*)d_in[1];
  const float* w1    = (const float*)d_in[2];
  const float* b1    = (const float*)d_in[3];
  const float* w2    = (const float*)d_in[4];
  const float* b2    = (const float*)d_in[5];
  const float* lw    = (const float*)d_in[6];
  const float* lbias = (const float*)d_in[7];
  float* out = (float*)d_out;
  unsigned short* lb = (unsigned short*)d_ws; // 64*608*2 = 77824 B

  prep_lb_kernel<<<(NCO * KPAD + 255) / 256, 256, 0, stream>>>(lw, lb);
  pointconv_kernel<<<NB * (NN / MT), 256, 0, stream>>>(
      xy, feat, w1, b1, w2, b2, lb, lbias, out);
}